// Round 17
// baseline (117.744 us; speedup 1.0000x reference)
//
#include <hip/hip_runtime.h>
#include <hip/hip_bf16.h>

// SpectralConv1d: out = irfft( pad( einsum('bjix,iox->bjox', rfft(x)[..:64], wr+i*wi) ), n=2048 )
// FUSED GEMM1+MIX, k-half split: block (bj,kh) computes A[bj, :, kh-half cols] over full K
// (grid 512 = 2 blocks/CU, 48 KB LDS), then mixes its k-half in-block -> pre-swizzled Bx.
// No P intermediate. -> GEMM2 (inverse DFT, BM=128 x BN=64, pure-DMA staging).

typedef __bf16 bf16x8 __attribute__((ext_vector_type(8)));
typedef float  f32x4  __attribute__((ext_vector_type(4)));

#define SEQ 2048
#define NM2 128   // 2*MODES (Re | Im planes)

__device__ __forceinline__ unsigned int rnbf(float f) {
  unsigned int u = __builtin_bit_cast(unsigned int, f);
  return (u + 0x7fffu + ((u >> 16) & 1u)) >> 16;  // round-to-nearest-even bf16
}
__device__ __forceinline__ unsigned int pack2(float a, float b) {
  return rnbf(a) | (rnbf(b) << 16);
}

typedef const __attribute__((address_space(1))) unsigned int gu32;
typedef __attribute__((address_space(3))) unsigned int lu32;

// ---------------- K0: trig tables (hw v_sin/v_cos, revolution args) ----------------
// t1sw: 32 tiles of 16 KB; tile kt = PRE-SWIZZLED LDS image of T1T[c][kt*64..+63]:
//       byte ((c*128 + part*16) ^ ((c&7)<<4)) + 2*e ; c<64: cos(2pi k n/N); c>=64: -sin
// t2sw: 16 tiles of 32 KB; tile nb = PRE-SWIZZLED image of T2 rows [nb*128, +128):
//       half h (Re|Im) at tile*32768 + h*16384; within half (row stride 128 B):
//       byte rl*128 + ((((k&63)>>3)*16) ^ ((rl&7)<<4)) + 2*(k&7), rl = n&127.
__global__ __launch_bounds__(256) void k_tables(unsigned short* __restrict__ t1sw,
                                                unsigned short* __restrict__ t2sw) {
  int idx = blockIdx.x * 256 + threadIdx.x;   // 0..131071
  int k = idx >> 11;                          // 0..63
  int n = idx & 2047;
  float rev = (float)((k * n) & 2047) * (1.0f / 2048.0f);   // phase in revolutions
  float s, co;
  asm("v_sin_f32 %0, %1" : "=v"(s)  : "v"(rev));
  asm("v_cos_f32 %0, %1" : "=v"(co) : "v"(rev));
  float ck = (k == 0 ? 1.0f : 2.0f) * (1.0f / 2048.0f);
  {
    int kt = n >> 6, part = (n >> 3) & 7, e = n & 7;
    unsigned base = (unsigned)kt * 16384u + 2u * (unsigned)e;
    unsigned offc = base + (((unsigned)(k * 128 + part * 16)) ^ (((unsigned)k & 7u) << 4));
    int c2 = k + 64;
    unsigned offs = base + (((unsigned)(c2 * 128 + part * 16)) ^ (((unsigned)c2 & 7u) << 4));
    *(unsigned short*)((char*)t1sw + offc) = (unsigned short)rnbf(co);
    *(unsigned short*)((char*)t1sw + offs) = (unsigned short)rnbf(-s);
  }
  {
    int tile = n >> 7, rl = n & 127;
    unsigned rowbase = (unsigned)tile * 32768u + (unsigned)rl * 128u;
    unsigned kpart = ((((unsigned)(k >> 3)) * 16u) ^ (((unsigned)rl & 7u) << 4)) + 2u * ((unsigned)k & 7u);
    *(unsigned short*)((char*)t2sw + rowbase + kpart)          = (unsigned short)rnbf(ck * co);
    *(unsigned short*)((char*)t2sw + rowbase + 16384u + kpart) = (unsigned short)rnbf(-ck * s);
  }
}

// ---------------- K1: FUSED  block (bj,kh): A-half = x[bj] @ T1[:,khcols]; mix -> Bx ----
// Grid 512 (2 blocks/CU), 256 threads (4 waves), LDS 48 KB:
//   xbuf0/1 fp32 [64][64] @ 0/16K ; t1buf0/1 bf16 64 local cols @ 32K/40K (8 KB each)
// Local col lc in [0,64): lc<32 -> Re(k=kh*32+lc); lc>=32 -> Im(k=kh*32+lc-32).
// Image row for local col lc = global c(lc) = kh*32 + (lc&31) + ((lc&32)<<1); c&7 == lc&7
// (kh*32 = 0 mod 8), so the baked intra-row XOR matches local-row indexing.
// Per iter (r15 schedule): issue STAGE(it+1) [4 x-DMA + 2 t1-DMA] -> compute -> vmcnt(0)
// -> barrier. 32 iters. Swapped MFMA (D^T): lane holds (row a, 4 consecutive local cols).
// Epilogue: A-half -> LDS fp32 [64][68], per-k complex mix (o=tid>>2, 8-k octet),
// write Bx pre-swizzled (one 16B span per half per thread).
__global__ __launch_bounds__(256) void k_gemm1f(const float* __restrict__ x,
                                                const unsigned short* __restrict__ t1sw,
                                                const float* __restrict__ wre,
                                                const float* __restrict__ wim,
                                                char* __restrict__ Bxsw) {
  __shared__ int4 lds4[49152 / 16];
  char* lds = (char*)lds4;
  const int tid = threadIdx.x, wave = tid >> 6, lane = tid & 63;
  const int bj = blockIdx.x >> 1, kh = blockIdx.x & 1;
  const int r0 = bj * 64;

  // x DMA sites p=0..3: row = p*16 + wave*4 + (lane>>4); 16B unit (lane&15)^(row&7)
  const float* xsrc[4];
#pragma unroll
  for (int p = 0; p < 4; ++p) {
    const int row = p * 16 + wave * 4 + (lane >> 4);
    const int u = (lane & 15) ^ (row & 7);
    xsrc[p] = x + (size_t)(r0 + row) * SEQ + u * 4;
  }
  // t1 DMA sites q=0,1: l = q*256+tid; local row rl = l>>3, part = l&7; global c(rl)
  const char* t1src[2];
#pragma unroll
  for (int q = 0; q < 2; ++q) {
    const int l = q * 256 + tid;
    const int rl = l >> 3, part = l & 7;
    const int c = kh * 32 + (rl & 31) + ((rl & 32) << 1);
    t1src[q] = (const char*)t1sw + c * 128 + part * 16;
  }

  f32x4 acc[4] = {};

#define XSTAGE(it, buf)                                                               \
  {                                                                                   \
    _Pragma("unroll")                                                                 \
    for (int p = 0; p < 4; ++p)                                                       \
      __builtin_amdgcn_global_load_lds((gu32*)(xsrc[p] + (it) * 64),                  \
          (lu32*)(lds + (buf) * 16384 + p * 4096 + wave * 1024), 16, 0, 0);           \
  }
#define TSTAGE(it, buf)                                                               \
  {                                                                                   \
    _Pragma("unroll")                                                                 \
    for (int q = 0; q < 2; ++q)                                                       \
      __builtin_amdgcn_global_load_lds((gu32*)(t1src[q] + (size_t)(it) * 16384),      \
          (lu32*)(lds + 32768 + (buf) * 8192 + q * 4096 + wave * 1024), 16, 0, 0);    \
  }

  // ---- prologue: stage tile 0 ----
  XSTAGE(0, 0);
  TSTAGE(0, 0);
  asm volatile("s_waitcnt vmcnt(0)" ::: "memory");
  __builtin_amdgcn_s_barrier();

  const int a = wave * 16 + (lane & 15);       // i-row of the A slab
  const unsigned xra = (unsigned)(a & 7) << 4;
  const int kg = lane >> 4;

  for (int it = 0; it < 32; ++it) {
    const int cur = it & 1, nxt = cur ^ 1;
    const int xoff = cur * 16384;
    const int toff = 32768 + cur * 8192;
    if (it < 31) {
      XSTAGE(it + 1, nxt);
      TSTAGE(it + 1, nxt);
    }
#pragma unroll
    for (int kss = 0; kss < 2; ++kss) {
      const unsigned byte0 = (unsigned)(a * 256 + kss * 128 + kg * 32);
      const f32x4 lo = *(const f32x4*)(lds + xoff + (byte0 ^ xra));
      const f32x4 hi = *(const f32x4*)(lds + xoff + ((byte0 + 16) ^ xra));
      unsigned c0, c1, c2, c3;
      asm("v_cvt_pk_bf16_f32 %0, %1, %2" : "=v"(c0) : "v"(lo[0]), "v"(lo[1]));
      asm("v_cvt_pk_bf16_f32 %0, %1, %2" : "=v"(c1) : "v"(lo[2]), "v"(lo[3]));
      asm("v_cvt_pk_bf16_f32 %0, %1, %2" : "=v"(c2) : "v"(hi[0]), "v"(hi[1]));
      asm("v_cvt_pk_bf16_f32 %0, %1, %2" : "=v"(c3) : "v"(hi[2]), "v"(hi[3]));
      uint4 pk; pk.x = c0; pk.y = c1; pk.z = c2; pk.w = c3;
      const bf16x8 av = __builtin_bit_cast(bf16x8, pk);
#pragma unroll
      for (int t = 0; t < 4; ++t) {
        const int lc = t * 16 + (lane & 15);   // local col
        const bf16x8 bv = *(const bf16x8*)(lds + toff +
            ((lc * 128 + kss * 64 + kg * 16) ^ ((unsigned)(lc & 7) << 4)));
        acc[t] = __builtin_amdgcn_mfma_f32_16x16x32_bf16(bv, av, acc[t], 0, 0, 0);  // D^T
      }
    }
    asm volatile("s_waitcnt vmcnt(0)" ::: "memory");
    __builtin_amdgcn_s_barrier();
  }
#undef XSTAGE
#undef TSTAGE

  // ---- epilogue 1: A-half slab -> LDS fp32 [64][68] (pad 68 -> conflict-free) ----
  float* sA = (float*)lds;
#pragma unroll
  for (int t = 0; t < 4; ++t) {
    const int lc0 = t * 16 + kg * 4;          // lane holds 4 consecutive local cols (D^T)
    *(f32x4*)(sA + a * 68 + lc0) = acc[t];
  }
  __syncthreads();

  // ---- epilogue 2: per-k complex mix. thread: o = tid>>2 (0..63), octet jb=(tid&3)*8 ----
  const int o = tid >> 2;
  const int jb = (tid & 3) * 8;               // local k (0..31), 8 wide
  const int kglo = kh * 32 + jb;              // global k
  f32x4 accr0 = {}, accr1 = {}, acci0 = {}, acci1 = {};
  for (int i = 0; i < 64; ++i) {
    const float* wp = wre + (size_t)(i * 64 + o) * 64 + kglo;
    const float* wq = wim + (size_t)(i * 64 + o) * 64 + kglo;
    const f32x4 w0 = *(const f32x4*)(wp),      w1 = *(const f32x4*)(wp + 4);
    const f32x4 v0 = *(const f32x4*)(wq),      v1 = *(const f32x4*)(wq + 4);
    const float* ap = sA + i * 68 + jb;
    const f32x4 ar0 = *(const f32x4*)(ap),      ar1 = *(const f32x4*)(ap + 4);
    const f32x4 ai0 = *(const f32x4*)(ap + 32), ai1 = *(const f32x4*)(ap + 36);
#pragma unroll
    for (int kk = 0; kk < 4; ++kk) {
      accr0[kk] += ar0[kk] * w0[kk] - ai0[kk] * v0[kk];
      accr1[kk] += ar1[kk] * w1[kk] - ai1[kk] * v1[kk];
      acci0[kk] += ar0[kk] * v0[kk] + ai0[kk] * w0[kk];
      acci1[kk] += ar1[kk] * v1[kk] + ai1[kk] * w1[kk];
    }
  }
  // write Bx pre-swizzled: r = bj*64+o; 8 k of this thread = ONE 16B span per half
  const int r = bj * 64 + o;
  const int tile = r >> 7, rl = r & 127;
  char* bb = Bxsw + (size_t)tile * 32768 + (size_t)rl * 128;
  const unsigned kp0 = (((unsigned)(kglo >> 3)) * 16u) ^ (((unsigned)rl & 7u) << 4);
  uint4 vr; vr.x = pack2(accr0[0], accr0[1]); vr.y = pack2(accr0[2], accr0[3]);
            vr.z = pack2(accr1[0], accr1[1]); vr.w = pack2(accr1[2], accr1[3]);
  uint4 vi; vi.x = pack2(acci0[0], acci0[1]); vi.y = pack2(acci0[2], acci0[3]);
            vi.z = pack2(acci1[0], acci1[1]); vi.w = pack2(acci1[2], acci1[3]);
  *(uint4*)(bb + kp0)         = vr;   // Re half
  *(uint4*)(bb + 16384 + kp0) = vi;   // Im half
}

// ---------------- K3: GEMM2  out[16384][2048] = Bx[16384][128] @ T2 ----------------
// BM=128, BN=64, K=128. LDS 48 KB -> 3 blocks/CU. Pure-DMA staging from PRE-SWIZZLED
// images: full Bx mb-tile (32 KB) + the 64-row slice of the t2 nb-tile (16 KB).
// Half-pipelined: issue 12 gll -> vmcnt(6) -> barrier -> h0 -> vmcnt(0) -> barrier -> h1.
// Stores: per row 4 back-to-back 64B stores = contiguous 256B. Grid 4096, XCD swizzle.
__global__ __launch_bounds__(256) void k_gemm2(const char* __restrict__ Bxsw,
                                               const char* __restrict__ t2sw,
                                               float* __restrict__ out) {
  __shared__ int4 lds4[49152 / 16];   // [0,16K) Bx-h0 | [16K,32K) Bx-h1 | [32K,48K) t2 h0|h1
  char* lds = (char*)lds4;
  const int tid = threadIdx.x, wave = tid >> 6, lane = tid & 63;
  const int swz = (blockIdx.x & 7) * 512 + (blockIdx.x >> 3);   // XCD-contiguous (4096%8==0)
  const int mb = swz >> 5, nb64 = swz & 31;
  const int r0 = mb * 128, n0 = nb64 * 64;
  const char* bsrc = Bxsw + (size_t)mb * 32768;
  const char* tsrc = t2sw + (size_t)(nb64 >> 1) * 32768 + (size_t)(nb64 & 1) * 8192;  // row slice
#pragma unroll
  for (int i = 0; i < 4; ++i)
    __builtin_amdgcn_global_load_lds((gu32*)(bsrc + i * 4096 + tid * 16),
                                     (lu32*)(lds + i * 4096 + wave * 1024), 16, 0, 0);
#pragma unroll
  for (int i = 0; i < 2; ++i)
    __builtin_amdgcn_global_load_lds((gu32*)(tsrc + i * 4096 + tid * 16),
                                     (lu32*)(lds + 32768 + i * 4096 + wave * 1024), 16, 0, 0);
#pragma unroll
  for (int i = 0; i < 4; ++i)
    __builtin_amdgcn_global_load_lds((gu32*)(bsrc + 16384 + i * 4096 + tid * 16),
                                     (lu32*)(lds + 16384 + i * 4096 + wave * 1024), 16, 0, 0);
#pragma unroll
  for (int i = 0; i < 2; ++i)
    __builtin_amdgcn_global_load_lds((gu32*)(tsrc + 16384 + i * 4096 + tid * 16),
                                     (lu32*)(lds + 40960 + i * 4096 + wave * 1024), 16, 0, 0);
  asm volatile("s_waitcnt vmcnt(6)" ::: "memory");   // h0 of both operands landed
  __builtin_amdgcn_s_barrier();

  f32x4 acc[2][4] = {};
  const int rowA0 = wave * 32 + (lane & 15);
  const int rowA1 = rowA0 + 16;
  const unsigned xa0 = (unsigned)(rowA0 & 7) << 4;
  const unsigned xa1 = (unsigned)(rowA1 & 7) << 4;

#pragma unroll
  for (int half = 0; half < 2; ++half) {
    if (half == 1) {
      asm volatile("s_waitcnt vmcnt(0)" ::: "memory");
      __builtin_amdgcn_s_barrier();
    }
    const int ab = half * 16384;           // Bx half base
    const int bb = 32768 + half * 8192;    // t2 half base (64 rows x 128 B)
#pragma unroll
    for (int kq = 0; kq < 2; ++kq) {       // 32 k = 64 B per 128-B row
      const unsigned offh = (unsigned)(kq * 64 + (lane >> 4) * 16);
      const bf16x8 a0 = *(const bf16x8*)(lds + ab + rowA0 * 128 + (offh ^ xa0));
      const bf16x8 a1 = *(const bf16x8*)(lds + ab + rowA1 * 128 + (offh ^ xa1));
#pragma unroll
      for (int t = 0; t < 4; ++t) {
        const int rn = t * 16 + (lane & 15);
        const bf16x8 bv = *(const bf16x8*)(lds + bb + rn * 128 + (offh ^ ((unsigned)(rn & 7) << 4)));
        acc[0][t] = __builtin_amdgcn_mfma_f32_16x16x32_bf16(a0, bv, acc[0][t], 0, 0, 0);
        acc[1][t] = __builtin_amdgcn_mfma_f32_16x16x32_bf16(a1, bv, acc[1][t], 0, 0, 0);
      }
    }
  }
#pragma unroll
  for (int m = 0; m < 2; ++m) {
#pragma unroll
    for (int j = 0; j < 4; ++j) {
      const int row = r0 + wave * 32 + m * 16 + (lane >> 4) * 4 + j;
#pragma unroll
      for (int t = 0; t < 4; ++t) {
        const int col = n0 + t * 16 + (lane & 15);
        out[(size_t)row * SEQ + col] = acc[m][t][j];
      }
    }
  }
}

extern "C" void kernel_launch(void* const* d_in, const int* in_sizes, int n_in,
                              void* d_out, int out_size, void* d_ws, size_t ws_size,
                              hipStream_t stream) {
  const float* x  = (const float*)d_in[0];
  const float* wr = (const float*)d_in[1];
  const float* wi = (const float*)d_in[2];
  float* out = (float*)d_out;
  char* ws = (char*)d_ws;
  // ws layout: t1sw 512K | t2sw 512K | Bxsw 4M   (total ~5 MB; no P intermediate)
  unsigned short* t1sw = (unsigned short*)(ws);
  unsigned short* t2sw = (unsigned short*)(ws + 524288);
  char*           Bxsw = (char*)(ws + 1048576);

  k_tables<<<dim3(512),  dim3(256), 0, stream>>>(t1sw, t2sw);
  k_gemm1f<<<dim3(512),  dim3(256), 0, stream>>>(x, t1sw, wr, wi, Bxsw);
  k_gemm2 <<<dim3(4096), dim3(256), 0, stream>>>(Bxsw, (const char*)t2sw, out);
}

// Round 18
// 93.456 us; speedup vs baseline: 1.2599x; 1.2599x over previous
//
#include <hip/hip_runtime.h>
#include <hip/hip_bf16.h>

// SpectralConv1d: out = irfft( pad( einsum('bjix,iox->bjox', rfft(x)[..:64], wr+i*wi) ), n=2048 )
// GEMM1 (DFT, KS=4/BM=64, 8 iters/block, all-DMA dbuf staging, swapped-operand MFMA)
// -> stage2 (256 blocks, 4 bj, reduce 4 bf16 partials + complex mix; writes Bx PRE-SWIZZLED)
// -> GEMM2 (inverse DFT; BM=128 x BN=64, 48 KB LDS -> 3 blocks/CU, pure-DMA staging from
//    pre-swizzled Bx/t2 images, half-pipelined vmcnt(6); 256B-contiguous row stores).

typedef __bf16 bf16x8 __attribute__((ext_vector_type(8)));
typedef float  f32x4  __attribute__((ext_vector_type(4)));

#define SEQ 2048
#define NM2 128   // 2*MODES (Re | Im planes)
#define KS  4     // K-split for GEMM1 (K-slice 512, 8 iters/block)

__device__ __forceinline__ unsigned int rnbf(float f) {
  unsigned int u = __builtin_bit_cast(unsigned int, f);
  return (u + 0x7fffu + ((u >> 16) & 1u)) >> 16;  // round-to-nearest-even bf16
}
__device__ __forceinline__ unsigned int pack2(float a, float b) {
  return rnbf(a) | (rnbf(b) << 16);
}
__device__ __forceinline__ float frombf(unsigned int lo16_in_place) {
  return __builtin_bit_cast(float, lo16_in_place);
}

typedef const __attribute__((address_space(1))) unsigned int gu32;
typedef __attribute__((address_space(3))) unsigned int lu32;

// ---------------- K0: trig tables (hw v_sin/v_cos, revolution args) ----------------
// t1sw: 32 tiles of 16 KB; tile kt = PRE-SWIZZLED LDS image of T1T[c][kt*64..+63]:
//       byte ((c*128 + part*16) ^ ((c&7)<<4)) + 2*e ; c<64: cos(2pi k n/N); c>=64: -sin
// t2sw: 16 tiles of 32 KB; tile nb = PRE-SWIZZLED image of T2 rows [nb*128, +128):
//       half h (Re|Im) at tile*32768 + h*16384; within half (row stride 128 B):
//       byte rl*128 + ((((k&63)>>3)*16) ^ ((rl&7)<<4)) + 2*(k&7), rl = n&127.
__global__ __launch_bounds__(256) void k_tables(unsigned short* __restrict__ t1sw,
                                                unsigned short* __restrict__ t2sw) {
  int idx = blockIdx.x * 256 + threadIdx.x;   // 0..131071
  int k = idx >> 11;                          // 0..63
  int n = idx & 2047;
  float rev = (float)((k * n) & 2047) * (1.0f / 2048.0f);   // phase in revolutions
  float s, co;
  asm("v_sin_f32 %0, %1" : "=v"(s)  : "v"(rev));
  asm("v_cos_f32 %0, %1" : "=v"(co) : "v"(rev));
  float ck = (k == 0 ? 1.0f : 2.0f) * (1.0f / 2048.0f);
  {
    int kt = n >> 6, part = (n >> 3) & 7, e = n & 7;
    unsigned base = (unsigned)kt * 16384u + 2u * (unsigned)e;
    unsigned offc = base + (((unsigned)(k * 128 + part * 16)) ^ (((unsigned)k & 7u) << 4));
    int c2 = k + 64;
    unsigned offs = base + (((unsigned)(c2 * 128 + part * 16)) ^ (((unsigned)c2 & 7u) << 4));
    *(unsigned short*)((char*)t1sw + offc) = (unsigned short)rnbf(co);
    *(unsigned short*)((char*)t1sw + offs) = (unsigned short)rnbf(-s);
  }
  {
    int tile = n >> 7, rl = n & 127;
    unsigned rowbase = (unsigned)tile * 32768u + (unsigned)rl * 128u;
    unsigned kpart = ((((unsigned)(k >> 3)) * 16u) ^ (((unsigned)rl & 7u) << 4)) + 2u * ((unsigned)k & 7u);
    *(unsigned short*)((char*)t2sw + rowbase + kpart)          = (unsigned short)rnbf(ck * co);
    *(unsigned short*)((char*)t2sw + rowbase + 16384u + kpart) = (unsigned short)rnbf(-ck * s);
  }
}

// ---------------- K1: GEMM1  P[ks][16384][128] = x[.,Kslice] @ T1[Kslice,.]  (bf16) ----
// r15 schedule, KS=4: BM=64, BK=64, K-slice=512 (8 iters), grid 1024, 64 KB LDS dbuf,
// all staging via global_load_lds. Per iter: issue STAGE(it+1) -> compute(it) -> vmcnt(0)
// -> barrier. fp32->bf16 at fragment read. Swapped-operand MFMA (D^T) -> packed stores.
__global__ __launch_bounds__(256) void k_gemm1(const float* __restrict__ x,
                                               const unsigned short* __restrict__ t1sw,
                                               unsigned short* __restrict__ P) {
  __shared__ int4 lds4[65536 / 16];  // [0,32K): xbuf0/1 fp32 ; [32K,64K): t1buf0/1 bf16
  char* lds = (char*)lds4;
  const int tid = threadIdx.x, wave = tid >> 6, lane = tid & 63;
  const int mtile = blockIdx.x >> 2, ks = blockIdx.x & (KS - 1);
  const int r0 = mtile * 64;
  const int kbase = ks * (SEQ / KS);
  const char* t1base = (const char*)t1sw + (size_t)(kbase >> 6) * 16384;

  const float* xsrc[4];
#pragma unroll
  for (int p = 0; p < 4; ++p) {
    const int row = p * 16 + wave * 4 + (lane >> 4);
    const int u = (lane & 15) ^ (row & 7);
    xsrc[p] = x + (size_t)(r0 + row) * SEQ + kbase + u * 4;
  }

  f32x4 acc[8] = {};

#pragma unroll
  for (int p = 0; p < 4; ++p)
    __builtin_amdgcn_global_load_lds((gu32*)(xsrc[p]),
                                     (lu32*)(lds + p * 4096 + wave * 1024), 16, 0, 0);
#pragma unroll
  for (int p = 0; p < 4; ++p)
    __builtin_amdgcn_global_load_lds((gu32*)(t1base + (p * 256 + tid) * 16),
                                     (lu32*)(lds + 32768 + (p * 256 + wave * 64) * 16), 16, 0, 0);
  asm volatile("s_waitcnt vmcnt(0)" ::: "memory");
  __builtin_amdgcn_s_barrier();

  const int a = wave * 16 + (lane & 15);
  const unsigned xra = (unsigned)(a & 7) << 4;
  const int kg = lane >> 4;

  for (int it = 0; it < 8; ++it) {
    const int cur = it & 1, nxt = cur ^ 1;
    const int xoff = cur * 16384;
    const int toff = 32768 + cur * 16384;
    if (it < 7) {
      const char* tg = t1base + (size_t)(it + 1) * 16384;
#pragma unroll
      for (int p = 0; p < 4; ++p)
        __builtin_amdgcn_global_load_lds((gu32*)(xsrc[p] + (it + 1) * 64),
                                         (lu32*)(lds + nxt * 16384 + p * 4096 + wave * 1024),
                                         16, 0, 0);
#pragma unroll
      for (int p = 0; p < 4; ++p)
        __builtin_amdgcn_global_load_lds((gu32*)(tg + (p * 256 + tid) * 16),
                                         (lu32*)(lds + 32768 + nxt * 16384 + (p * 256 + wave * 64) * 16),
                                         16, 0, 0);
    }
#pragma unroll
    for (int kss = 0; kss < 2; ++kss) {
      const unsigned byte0 = (unsigned)(a * 256 + kss * 128 + kg * 32);
      const f32x4 lo = *(const f32x4*)(lds + xoff + (byte0 ^ xra));
      const f32x4 hi = *(const f32x4*)(lds + xoff + ((byte0 + 16) ^ xra));
      unsigned c0, c1, c2, c3;
      asm("v_cvt_pk_bf16_f32 %0, %1, %2" : "=v"(c0) : "v"(lo[0]), "v"(lo[1]));
      asm("v_cvt_pk_bf16_f32 %0, %1, %2" : "=v"(c1) : "v"(lo[2]), "v"(lo[3]));
      asm("v_cvt_pk_bf16_f32 %0, %1, %2" : "=v"(c2) : "v"(hi[0]), "v"(hi[1]));
      asm("v_cvt_pk_bf16_f32 %0, %1, %2" : "=v"(c3) : "v"(hi[2]), "v"(hi[3]));
      uint4 pk; pk.x = c0; pk.y = c1; pk.z = c2; pk.w = c3;
      const bf16x8 av = __builtin_bit_cast(bf16x8, pk);
#pragma unroll
      for (int t = 0; t < 8; ++t) {
        const int col = t * 16 + (lane & 15);
        const bf16x8 bv = *(const bf16x8*)(lds + toff +
            ((col * 128 + kss * 64 + kg * 16) ^ ((unsigned)(col & 7) << 4)));
        acc[t] = __builtin_amdgcn_mfma_f32_16x16x32_bf16(bv, av, acc[t], 0, 0, 0);  // D^T
      }
    }
    asm volatile("s_waitcnt vmcnt(0)" ::: "memory");
    __builtin_amdgcn_s_barrier();
  }
  unsigned short* Pout = P + (size_t)ks * (16384 * NM2);
  const int row = r0 + wave * 16 + (lane & 15);
#pragma unroll
  for (int t = 0; t < 8; ++t) {
    const int col0 = t * 16 + kg * 4;
    uint2 v; v.x = pack2(acc[t][0], acc[t][1]); v.y = pack2(acc[t][2], acc[t][3]);
    *(uint2*)(Pout + (size_t)row * NM2 + col0) = v;
  }
}

// ---------------- K2: reduce bf16 partials + complex channel mix (fp32 VALU) ---------
// A = sum_ks P[ks]; B[bj,o,k] = sum_i (Ar+iAi)[bj,i,k]*(wr+iwi)[i,o,k].
// Writes Bx PRE-SWIZZLED (gemm2 tile images): tile r>>7, half (Re=0/Im=1), row r&127.
__global__ __launch_bounds__(256) void k_stage2(const unsigned short* __restrict__ P,
                                                const float* __restrict__ wr,
                                                const float* __restrict__ wi,
                                                char* __restrict__ Bxsw) {
  __shared__ float sA[4][64][64];   // [bj][i][ 0..31: Ar(k0+c) | 32..63: Ai(k0+c) ]
  const int b = blockIdx.x;
  const int bjc = b >> 2, oh = (b >> 1) & 1, kh = b & 1;
  const int k0 = kh * 32;
  const int tid = threadIdx.x;
#pragma unroll
  for (int p = 0; p < 16; ++p) {
    int fidx = tid + 256 * p;               // quad index 0..4095
    int row_lin = fidx >> 4, q = fidx & 15;
    int col = (q < 8) ? (k0 + q * 4) : (64 + k0 + (q - 8) * 4);
    const unsigned short* base = P + (size_t)(bjc * 256 + row_lin) * NM2 + col;
    f32x4 v = {};
#pragma unroll
    for (int s = 0; s < KS; ++s) {
      uint2 u = *(const uint2*)(base + (size_t)s * (16384 * NM2));
      v[0] += frombf(u.x << 16);
      v[1] += frombf(u.x & 0xffff0000u);
      v[2] += frombf(u.y << 16);
      v[3] += frombf(u.y & 0xffff0000u);
    }
    *(f32x4*)(&sA[row_lin >> 6][row_lin & 63][q * 4]) = v;
  }
  __syncthreads();
  const int o_l = tid >> 3, kg = tid & 7;
  const int o = oh * 32 + o_l;
  const int kb = k0 + kg * 4;
  f32x4 accr[4] = {};
  f32x4 acci[4] = {};
  for (int i = 0; i < 64; ++i) {
    f32x4 wrv = *(const f32x4*)(wr + (i * 64 + o) * 64 + kb);
    f32x4 wiv = *(const f32x4*)(wi + (i * 64 + o) * 64 + kb);
#pragma unroll
    for (int bj = 0; bj < 4; ++bj) {
      f32x4 ar = *(const f32x4*)(&sA[bj][i][kg * 4]);
      f32x4 ai = *(const f32x4*)(&sA[bj][i][32 + kg * 4]);
#pragma unroll
      for (int kk = 0; kk < 4; ++kk) {
        accr[bj][kk] += ar[kk] * wrv[kk] - ai[kk] * wiv[kk];
        acci[bj][kk] += ar[kk] * wiv[kk] + ai[kk] * wrv[kk];
      }
    }
  }
#pragma unroll
  for (int bj = 0; bj < 4; ++bj) {
    const int r = (bjc * 4 + bj) * 64 + o;
    const int tile = r >> 7, rl = r & 127;
    char* bb = Bxsw + (size_t)tile * 32768 + (size_t)rl * 128;
    const unsigned kp = ((((unsigned)kb >> 3) * 16u) ^ (((unsigned)rl & 7u) << 4)) + 2u * ((unsigned)kb & 7u);
    uint2 vr; vr.x = pack2(accr[bj][0], accr[bj][1]); vr.y = pack2(accr[bj][2], accr[bj][3]);
    uint2 vi; vi.x = pack2(acci[bj][0], acci[bj][1]); vi.y = pack2(acci[bj][2], acci[bj][3]);
    *(uint2*)(bb + kp)          = vr;   // Re half
    *(uint2*)(bb + 16384 + kp)  = vi;   // Im half
  }
}

// ---------------- K3: GEMM2  out[16384][2048] = Bx[16384][128] @ T2 ----------------
// BM=128, BN=64, K=128. LDS 48 KB -> 3 blocks/CU. Pure-DMA staging from PRE-SWIZZLED
// images: full Bx mb-tile (32 KB) + the 64-row slice of the t2 nb-tile (16 KB).
// Half-pipelined: issue 12 gll -> vmcnt(6) -> barrier -> h0 -> vmcnt(0) -> barrier -> h1.
// Stores: per row 4 back-to-back 64B stores = contiguous 256B. Grid 4096, XCD swizzle.
__global__ __launch_bounds__(256) void k_gemm2(const char* __restrict__ Bxsw,
                                               const char* __restrict__ t2sw,
                                               float* __restrict__ out) {
  __shared__ int4 lds4[49152 / 16];   // [0,16K) Bx-h0 | [16K,32K) Bx-h1 | [32K,48K) t2 h0|h1
  char* lds = (char*)lds4;
  const int tid = threadIdx.x, wave = tid >> 6, lane = tid & 63;
  const int swz = (blockIdx.x & 7) * 512 + (blockIdx.x >> 3);   // XCD-contiguous (4096%8==0)
  const int mb = swz >> 5, nb64 = swz & 31;
  const int r0 = mb * 128, n0 = nb64 * 64;
  const char* bsrc = Bxsw + (size_t)mb * 32768;
  const char* tsrc = t2sw + (size_t)(nb64 >> 1) * 32768 + (size_t)(nb64 & 1) * 8192;  // row slice
#pragma unroll
  for (int i = 0; i < 4; ++i)
    __builtin_amdgcn_global_load_lds((gu32*)(bsrc + i * 4096 + tid * 16),
                                     (lu32*)(lds + i * 4096 + wave * 1024), 16, 0, 0);
#pragma unroll
  for (int i = 0; i < 2; ++i)
    __builtin_amdgcn_global_load_lds((gu32*)(tsrc + i * 4096 + tid * 16),
                                     (lu32*)(lds + 32768 + i * 4096 + wave * 1024), 16, 0, 0);
#pragma unroll
  for (int i = 0; i < 4; ++i)
    __builtin_amdgcn_global_load_lds((gu32*)(bsrc + 16384 + i * 4096 + tid * 16),
                                     (lu32*)(lds + 16384 + i * 4096 + wave * 1024), 16, 0, 0);
#pragma unroll
  for (int i = 0; i < 2; ++i)
    __builtin_amdgcn_global_load_lds((gu32*)(tsrc + 16384 + i * 4096 + tid * 16),
                                     (lu32*)(lds + 40960 + i * 4096 + wave * 1024), 16, 0, 0);
  asm volatile("s_waitcnt vmcnt(6)" ::: "memory");   // h0 of both operands landed
  __builtin_amdgcn_s_barrier();

  f32x4 acc[2][4] = {};
  const int rowA0 = wave * 32 + (lane & 15);
  const int rowA1 = rowA0 + 16;
  const unsigned xa0 = (unsigned)(rowA0 & 7) << 4;
  const unsigned xa1 = (unsigned)(rowA1 & 7) << 4;

#pragma unroll
  for (int half = 0; half < 2; ++half) {
    if (half == 1) {
      asm volatile("s_waitcnt vmcnt(0)" ::: "memory");
      __builtin_amdgcn_s_barrier();
    }
    const int ab = half * 16384;           // Bx half base
    const int bb = 32768 + half * 8192;    // t2 half base (64 rows x 128 B)
#pragma unroll
    for (int kq = 0; kq < 2; ++kq) {       // 32 k = 64 B per 128-B row
      const unsigned offh = (unsigned)(kq * 64 + (lane >> 4) * 16);
      const bf16x8 a0 = *(const bf16x8*)(lds + ab + rowA0 * 128 + (offh ^ xa0));
      const bf16x8 a1 = *(const bf16x8*)(lds + ab + rowA1 * 128 + (offh ^ xa1));
#pragma unroll
      for (int t = 0; t < 4; ++t) {
        const int rn = t * 16 + (lane & 15);
        const bf16x8 bv = *(const bf16x8*)(lds + bb + rn * 128 + (offh ^ ((unsigned)(rn & 7) << 4)));
        acc[0][t] = __builtin_amdgcn_mfma_f32_16x16x32_bf16(a0, bv, acc[0][t], 0, 0, 0);
        acc[1][t] = __builtin_amdgcn_mfma_f32_16x16x32_bf16(a1, bv, acc[1][t], 0, 0, 0);
      }
    }
  }
  // store: t innermost -> per row 4 back-to-back 64B stores = contiguous 256B
#pragma unroll
  for (int m = 0; m < 2; ++m) {
#pragma unroll
    for (int j = 0; j < 4; ++j) {
      const int row = r0 + wave * 32 + m * 16 + (lane >> 4) * 4 + j;
#pragma unroll
      for (int t = 0; t < 4; ++t) {
        const int col = n0 + t * 16 + (lane & 15);
        out[(size_t)row * SEQ + col] = acc[m][t][j];
      }
    }
  }
}

extern "C" void kernel_launch(void* const* d_in, const int* in_sizes, int n_in,
                              void* d_out, int out_size, void* d_ws, size_t ws_size,
                              hipStream_t stream) {
  const float* x  = (const float*)d_in[0];
  const float* wr = (const float*)d_in[1];
  const float* wi = (const float*)d_in[2];
  float* out = (float*)d_out;
  char* ws = (char*)d_ws;
  // ws layout: t1sw 512K | t2sw 512K | P (bf16) 4x4M = 16M | Bxsw 4M   (total ~21 MB)
  unsigned short* t1sw = (unsigned short*)(ws);
  unsigned short* t2sw = (unsigned short*)(ws + 524288);
  unsigned short* P    = (unsigned short*)(ws + 1048576);
  char*           Bxsw = (char*)(ws + 1048576 + (size_t)KS * 16384 * NM2 * 2);

  k_tables<<<dim3(512),      dim3(256), 0, stream>>>(t1sw, t2sw);
  k_gemm1 <<<dim3(256 * KS), dim3(256), 0, stream>>>(x, t1sw, P);
  k_stage2<<<dim3(256),      dim3(256), 0, stream>>>(P, wr, wi, Bxsw);
  k_gemm2 <<<dim3(4096),     dim3(256), 0, stream>>>(Bxsw, (const char*)t2sw, out);
}

// Round 19
// 88.583 us; speedup vs baseline: 1.3292x; 1.0550x over previous
//
#include <hip/hip_runtime.h>
#include <hip/hip_bf16.h>

// SpectralConv1d: out = irfft( pad( einsum('bjix,iox->bjox', rfft(x)[..:64], wr+i*wi) ), n=2048 )
// GEMM1 (DFT, KS=2/BM=64, all-DMA dbuf staging, swapped-operand MFMA epilogue)
// -> stage2 (256 blocks, 4 bj, reduce bf16 partials + complex mix; writes Bx PRE-SWIZZLED)
// -> GEMM2 (inverse DFT; BM=128 x BN=64, 48 KB LDS -> 3 blocks/CU, pure-DMA staging from
//    pre-swizzled Bx/t2 images, half-pipelined vmcnt(6); 256B-contiguous row stores).
// [r19 = byte-exact revert to the session-best r15 configuration, 88.6 us measured]

typedef __bf16 bf16x8 __attribute__((ext_vector_type(8)));
typedef float  f32x4  __attribute__((ext_vector_type(4)));

#define SEQ 2048
#define NM2 128   // 2*MODES (Re | Im planes)
#define KS  2     // K-split for GEMM1

__device__ __forceinline__ unsigned int rnbf(float f) {
  unsigned int u = __builtin_bit_cast(unsigned int, f);
  return (u + 0x7fffu + ((u >> 16) & 1u)) >> 16;  // round-to-nearest-even bf16
}
__device__ __forceinline__ unsigned int pack2(float a, float b) {
  return rnbf(a) | (rnbf(b) << 16);
}
__device__ __forceinline__ float frombf(unsigned int lo16_in_place) {
  return __builtin_bit_cast(float, lo16_in_place);
}

typedef const __attribute__((address_space(1))) unsigned int gu32;
typedef __attribute__((address_space(3))) unsigned int lu32;

// ---------------- K0: trig tables (hw v_sin/v_cos, revolution args) ----------------
// t1sw: 32 tiles of 16 KB; tile kt = PRE-SWIZZLED LDS image of T1T[c][kt*64..+63]:
//       byte ((c*128 + part*16) ^ ((c&7)<<4)) + 2*e ; c<64: cos(2pi k n/N); c>=64: -sin
// t2sw: 16 tiles of 32 KB; tile nb = PRE-SWIZZLED image of T2 rows [nb*128, +128):
//       half h (Re|Im) at tile*32768 + h*16384; within half (row stride 128 B):
//       byte rl*128 + ((((k&63)>>3)*16) ^ ((rl&7)<<4)) + 2*(k&7), rl = n&127.
__global__ __launch_bounds__(256) void k_tables(unsigned short* __restrict__ t1sw,
                                                unsigned short* __restrict__ t2sw) {
  int idx = blockIdx.x * 256 + threadIdx.x;   // 0..131071
  int k = idx >> 11;                          // 0..63
  int n = idx & 2047;
  float rev = (float)((k * n) & 2047) * (1.0f / 2048.0f);   // phase in revolutions
  float s, co;
  asm("v_sin_f32 %0, %1" : "=v"(s)  : "v"(rev));
  asm("v_cos_f32 %0, %1" : "=v"(co) : "v"(rev));
  float ck = (k == 0 ? 1.0f : 2.0f) * (1.0f / 2048.0f);
  {
    int kt = n >> 6, part = (n >> 3) & 7, e = n & 7;
    unsigned base = (unsigned)kt * 16384u + 2u * (unsigned)e;
    unsigned offc = base + (((unsigned)(k * 128 + part * 16)) ^ (((unsigned)k & 7u) << 4));
    int c2 = k + 64;
    unsigned offs = base + (((unsigned)(c2 * 128 + part * 16)) ^ (((unsigned)c2 & 7u) << 4));
    *(unsigned short*)((char*)t1sw + offc) = (unsigned short)rnbf(co);
    *(unsigned short*)((char*)t1sw + offs) = (unsigned short)rnbf(-s);
  }
  {
    int tile = n >> 7, rl = n & 127;
    unsigned rowbase = (unsigned)tile * 32768u + (unsigned)rl * 128u;
    unsigned kpart = ((((unsigned)(k >> 3)) * 16u) ^ (((unsigned)rl & 7u) << 4)) + 2u * ((unsigned)k & 7u);
    *(unsigned short*)((char*)t2sw + rowbase + kpart)          = (unsigned short)rnbf(ck * co);
    *(unsigned short*)((char*)t2sw + rowbase + 16384u + kpart) = (unsigned short)rnbf(-ck * s);
  }
}

// ---------------- K1: GEMM1  P[ks][16384][128] = x[.,Kslice] @ T1[Kslice,.]  (bf16) ----
// r4 schedule: BM=64, BK=64, K-slice=1024 (16 iters), 64 KB LDS double-buffer, all
// staging via global_load_lds. Per iter: issue STAGE(it+1) -> compute(it) -> vmcnt(0)
// -> barrier. fp32->bf16 at fragment read. Swapped-operand MFMA (D^T) -> packed stores.
__global__ __launch_bounds__(256) void k_gemm1(const float* __restrict__ x,
                                               const unsigned short* __restrict__ t1sw,
                                               unsigned short* __restrict__ P) {
  __shared__ int4 lds4[65536 / 16];  // [0,32K): xbuf0/1 fp32 ; [32K,64K): t1buf0/1 bf16
  char* lds = (char*)lds4;
  const int tid = threadIdx.x, wave = tid >> 6, lane = tid & 63;
  const int mtile = blockIdx.x >> 1, ks = blockIdx.x & (KS - 1);
  const int r0 = mtile * 64;
  const int kbase = ks * (SEQ / KS);
  const char* t1base = (const char*)t1sw + (size_t)(kbase >> 6) * 16384;

  const float* xsrc[4];
#pragma unroll
  for (int p = 0; p < 4; ++p) {
    const int row = p * 16 + wave * 4 + (lane >> 4);
    const int u = (lane & 15) ^ (row & 7);
    xsrc[p] = x + (size_t)(r0 + row) * SEQ + kbase + u * 4;
  }

  f32x4 acc[8] = {};

#pragma unroll
  for (int p = 0; p < 4; ++p)
    __builtin_amdgcn_global_load_lds((gu32*)(xsrc[p]),
                                     (lu32*)(lds + p * 4096 + wave * 1024), 16, 0, 0);
#pragma unroll
  for (int p = 0; p < 4; ++p)
    __builtin_amdgcn_global_load_lds((gu32*)(t1base + (p * 256 + tid) * 16),
                                     (lu32*)(lds + 32768 + (p * 256 + wave * 64) * 16), 16, 0, 0);
  asm volatile("s_waitcnt vmcnt(0)" ::: "memory");
  __builtin_amdgcn_s_barrier();

  const int a = wave * 16 + (lane & 15);
  const unsigned xra = (unsigned)(a & 7) << 4;
  const int kg = lane >> 4;

  for (int it = 0; it < 16; ++it) {
    const int cur = it & 1, nxt = cur ^ 1;
    const int xoff = cur * 16384;
    const int toff = 32768 + cur * 16384;
    if (it < 15) {
      const char* tg = t1base + (size_t)(it + 1) * 16384;
#pragma unroll
      for (int p = 0; p < 4; ++p)
        __builtin_amdgcn_global_load_lds((gu32*)(xsrc[p] + (it + 1) * 64),
                                         (lu32*)(lds + nxt * 16384 + p * 4096 + wave * 1024),
                                         16, 0, 0);
#pragma unroll
      for (int p = 0; p < 4; ++p)
        __builtin_amdgcn_global_load_lds((gu32*)(tg + (p * 256 + tid) * 16),
                                         (lu32*)(lds + 32768 + nxt * 16384 + (p * 256 + wave * 64) * 16),
                                         16, 0, 0);
    }
#pragma unroll
    for (int kss = 0; kss < 2; ++kss) {
      const unsigned byte0 = (unsigned)(a * 256 + kss * 128 + kg * 32);
      const f32x4 lo = *(const f32x4*)(lds + xoff + (byte0 ^ xra));
      const f32x4 hi = *(const f32x4*)(lds + xoff + ((byte0 + 16) ^ xra));
      unsigned c0, c1, c2, c3;
      asm("v_cvt_pk_bf16_f32 %0, %1, %2" : "=v"(c0) : "v"(lo[0]), "v"(lo[1]));
      asm("v_cvt_pk_bf16_f32 %0, %1, %2" : "=v"(c1) : "v"(lo[2]), "v"(lo[3]));
      asm("v_cvt_pk_bf16_f32 %0, %1, %2" : "=v"(c2) : "v"(hi[0]), "v"(hi[1]));
      asm("v_cvt_pk_bf16_f32 %0, %1, %2" : "=v"(c3) : "v"(hi[2]), "v"(hi[3]));
      uint4 pk; pk.x = c0; pk.y = c1; pk.z = c2; pk.w = c3;
      const bf16x8 av = __builtin_bit_cast(bf16x8, pk);
#pragma unroll
      for (int t = 0; t < 8; ++t) {
        const int col = t * 16 + (lane & 15);
        const bf16x8 bv = *(const bf16x8*)(lds + toff +
            ((col * 128 + kss * 64 + kg * 16) ^ ((unsigned)(col & 7) << 4)));
        acc[t] = __builtin_amdgcn_mfma_f32_16x16x32_bf16(bv, av, acc[t], 0, 0, 0);  // D^T
      }
    }
    asm volatile("s_waitcnt vmcnt(0)" ::: "memory");
    __builtin_amdgcn_s_barrier();
  }
  unsigned short* Pout = P + (size_t)ks * (16384 * NM2);
  const int row = r0 + wave * 16 + (lane & 15);
#pragma unroll
  for (int t = 0; t < 8; ++t) {
    const int col0 = t * 16 + kg * 4;
    uint2 v; v.x = pack2(acc[t][0], acc[t][1]); v.y = pack2(acc[t][2], acc[t][3]);
    *(uint2*)(Pout + (size_t)row * NM2 + col0) = v;
  }
}

// ---------------- K2: reduce bf16 partials + complex channel mix (fp32 VALU) ---------
// A = sum_ks P[ks]; B[bj,o,k] = sum_i (Ar+iAi)[bj,i,k]*(wr+iwi)[i,o,k].
// Writes Bx PRE-SWIZZLED (gemm2 tile images): tile r>>7, half (Re=0/Im=1), row r&127.
__global__ __launch_bounds__(256) void k_stage2(const unsigned short* __restrict__ P,
                                                const float* __restrict__ wr,
                                                const float* __restrict__ wi,
                                                char* __restrict__ Bxsw) {
  __shared__ float sA[4][64][64];   // [bj][i][ 0..31: Ar(k0+c) | 32..63: Ai(k0+c) ]
  const int b = blockIdx.x;
  const int bjc = b >> 2, oh = (b >> 1) & 1, kh = b & 1;
  const int k0 = kh * 32;
  const int tid = threadIdx.x;
#pragma unroll
  for (int p = 0; p < 16; ++p) {
    int fidx = tid + 256 * p;               // quad index 0..4095
    int row_lin = fidx >> 4, q = fidx & 15;
    int col = (q < 8) ? (k0 + q * 4) : (64 + k0 + (q - 8) * 4);
    const unsigned short* base = P + (size_t)(bjc * 256 + row_lin) * NM2 + col;
    f32x4 v = {};
#pragma unroll
    for (int s = 0; s < KS; ++s) {
      uint2 u = *(const uint2*)(base + (size_t)s * (16384 * NM2));
      v[0] += frombf(u.x << 16);
      v[1] += frombf(u.x & 0xffff0000u);
      v[2] += frombf(u.y << 16);
      v[3] += frombf(u.y & 0xffff0000u);
    }
    *(f32x4*)(&sA[row_lin >> 6][row_lin & 63][q * 4]) = v;
  }
  __syncthreads();
  const int o_l = tid >> 3, kg = tid & 7;
  const int o = oh * 32 + o_l;
  const int kb = k0 + kg * 4;
  f32x4 accr[4] = {};
  f32x4 acci[4] = {};
  for (int i = 0; i < 64; ++i) {
    f32x4 wrv = *(const f32x4*)(wr + (i * 64 + o) * 64 + kb);
    f32x4 wiv = *(const f32x4*)(wi + (i * 64 + o) * 64 + kb);
#pragma unroll
    for (int bj = 0; bj < 4; ++bj) {
      f32x4 ar = *(const f32x4*)(&sA[bj][i][kg * 4]);
      f32x4 ai = *(const f32x4*)(&sA[bj][i][32 + kg * 4]);
#pragma unroll
      for (int kk = 0; kk < 4; ++kk) {
        accr[bj][kk] += ar[kk] * wrv[kk] - ai[kk] * wiv[kk];
        acci[bj][kk] += ar[kk] * wiv[kk] + ai[kk] * wrv[kk];
      }
    }
  }
#pragma unroll
  for (int bj = 0; bj < 4; ++bj) {
    const int r = (bjc * 4 + bj) * 64 + o;
    const int tile = r >> 7, rl = r & 127;
    char* bb = Bxsw + (size_t)tile * 32768 + (size_t)rl * 128;
    const unsigned kp = ((((unsigned)kb >> 3) * 16u) ^ (((unsigned)rl & 7u) << 4)) + 2u * ((unsigned)kb & 7u);
    uint2 vr; vr.x = pack2(accr[bj][0], accr[bj][1]); vr.y = pack2(accr[bj][2], accr[bj][3]);
    uint2 vi; vi.x = pack2(acci[bj][0], acci[bj][1]); vi.y = pack2(acci[bj][2], acci[bj][3]);
    *(uint2*)(bb + kp)          = vr;   // Re half
    *(uint2*)(bb + 16384 + kp)  = vi;   // Im half
  }
}

// ---------------- K3: GEMM2  out[16384][2048] = Bx[16384][128] @ T2 ----------------
// BM=128, BN=64, K=128. LDS 48 KB -> 3 blocks/CU. Pure-DMA staging from PRE-SWIZZLED
// images: full Bx mb-tile (32 KB) + the 64-row slice of the t2 nb-tile (16 KB).
// Half-pipelined: issue 12 gll -> vmcnt(6) -> barrier -> h0 -> vmcnt(0) -> barrier -> h1.
// Stores: per row 4 back-to-back 64B stores = contiguous 256B. Grid 4096, XCD swizzle.
__global__ __launch_bounds__(256) void k_gemm2(const char* __restrict__ Bxsw,
                                               const char* __restrict__ t2sw,
                                               float* __restrict__ out) {
  __shared__ int4 lds4[49152 / 16];   // [0,16K) Bx-h0 | [16K,32K) Bx-h1 | [32K,48K) t2 h0|h1
  char* lds = (char*)lds4;
  const int tid = threadIdx.x, wave = tid >> 6, lane = tid & 63;
  const int swz = (blockIdx.x & 7) * 512 + (blockIdx.x >> 3);   // XCD-contiguous (4096%8==0)
  const int mb = swz >> 5, nb64 = swz & 31;
  const int r0 = mb * 128, n0 = nb64 * 64;
  const char* bsrc = Bxsw + (size_t)mb * 32768;
  const char* tsrc = t2sw + (size_t)(nb64 >> 1) * 32768 + (size_t)(nb64 & 1) * 8192;  // row slice
#pragma unroll
  for (int i = 0; i < 4; ++i)
    __builtin_amdgcn_global_load_lds((gu32*)(bsrc + i * 4096 + tid * 16),
                                     (lu32*)(lds + i * 4096 + wave * 1024), 16, 0, 0);
#pragma unroll
  for (int i = 0; i < 2; ++i)
    __builtin_amdgcn_global_load_lds((gu32*)(tsrc + i * 4096 + tid * 16),
                                     (lu32*)(lds + 32768 + i * 4096 + wave * 1024), 16, 0, 0);
#pragma unroll
  for (int i = 0; i < 4; ++i)
    __builtin_amdgcn_global_load_lds((gu32*)(bsrc + 16384 + i * 4096 + tid * 16),
                                     (lu32*)(lds + 16384 + i * 4096 + wave * 1024), 16, 0, 0);
#pragma unroll
  for (int i = 0; i < 2; ++i)
    __builtin_amdgcn_global_load_lds((gu32*)(tsrc + 16384 + i * 4096 + tid * 16),
                                     (lu32*)(lds + 40960 + i * 4096 + wave * 1024), 16, 0, 0);
  asm volatile("s_waitcnt vmcnt(6)" ::: "memory");   // h0 of both operands landed
  __builtin_amdgcn_s_barrier();

  f32x4 acc[2][4] = {};
  const int rowA0 = wave * 32 + (lane & 15);
  const int rowA1 = rowA0 + 16;
  const unsigned xa0 = (unsigned)(rowA0 & 7) << 4;
  const unsigned xa1 = (unsigned)(rowA1 & 7) << 4;

#pragma unroll
  for (int half = 0; half < 2; ++half) {
    if (half == 1) {
      asm volatile("s_waitcnt vmcnt(0)" ::: "memory");
      __builtin_amdgcn_s_barrier();
    }
    const int ab = half * 16384;           // Bx half base
    const int bb = 32768 + half * 8192;    // t2 half base (64 rows x 128 B)
#pragma unroll
    for (int kq = 0; kq < 2; ++kq) {       // 32 k = 64 B per 128-B row
      const unsigned offh = (unsigned)(kq * 64 + (lane >> 4) * 16);
      const bf16x8 a0 = *(const bf16x8*)(lds + ab + rowA0 * 128 + (offh ^ xa0));
      const bf16x8 a1 = *(const bf16x8*)(lds + ab + rowA1 * 128 + (offh ^ xa1));
#pragma unroll
      for (int t = 0; t < 4; ++t) {
        const int rn = t * 16 + (lane & 15);
        const bf16x8 bv = *(const bf16x8*)(lds + bb + rn * 128 + (offh ^ ((unsigned)(rn & 7) << 4)));
        acc[0][t] = __builtin_amdgcn_mfma_f32_16x16x32_bf16(a0, bv, acc[0][t], 0, 0, 0);
        acc[1][t] = __builtin_amdgcn_mfma_f32_16x16x32_bf16(a1, bv, acc[1][t], 0, 0, 0);
      }
    }
  }
  // store: t innermost -> per row 4 back-to-back 64B stores = contiguous 256B
#pragma unroll
  for (int m = 0; m < 2; ++m) {
#pragma unroll
    for (int j = 0; j < 4; ++j) {
      const int row = r0 + wave * 32 + m * 16 + (lane >> 4) * 4 + j;
#pragma unroll
      for (int t = 0; t < 4; ++t) {
        const int col = n0 + t * 16 + (lane & 15);
        out[(size_t)row * SEQ + col] = acc[m][t][j];
      }
    }
  }
}

extern "C" void kernel_launch(void* const* d_in, const int* in_sizes, int n_in,
                              void* d_out, int out_size, void* d_ws, size_t ws_size,
                              hipStream_t stream) {
  const float* x  = (const float*)d_in[0];
  const float* wr = (const float*)d_in[1];
  const float* wi = (const float*)d_in[2];
  float* out = (float*)d_out;
  char* ws = (char*)d_ws;
  // ws layout: t1sw 512K | t2sw 512K | P (bf16) 2x4M = 8M | Bxsw 4M   (total ~13 MB)
  unsigned short* t1sw = (unsigned short*)(ws);
  unsigned short* t2sw = (unsigned short*)(ws + 524288);
  unsigned short* P    = (unsigned short*)(ws + 1048576);
  char*           Bxsw = (char*)(ws + 1048576 + (size_t)KS * 16384 * NM2 * 2);

  k_tables<<<dim3(512),      dim3(256), 0, stream>>>(t1sw, t2sw);
  k_gemm1 <<<dim3(256 * KS), dim3(256), 0, stream>>>(x, t1sw, P);
  k_stage2<<<dim3(256),      dim3(256), 0, stream>>>(P, wr, wi, Bxsw);
  k_gemm2 <<<dim3(4096),     dim3(256), 0, stream>>>(Bxsw, (const char*)t2sw, out);
}